// Round 13
// baseline (97.054 us; speedup 1.0000x reference)
//
#include <hip/hip_runtime.h>

#define IC 3
#define OCH 16
#define IDD 16
#define IHH 32
#define IWW 32
#define ODD 31
#define OHH 63
#define OWW 63
#define NB 32

typedef float f2 __attribute__((ext_vector_type(2)));
typedef float f4 __attribute__((ext_vector_type(4)));

#define LOG2E 1.44269504088896340736f
#define LN2   0.69314718055994530942f
#define SIX_EXP_M3 0.2987224102071593f   // 6*e^-3

static __device__ __forceinline__ f2 fma2(f2 a, f2 b, f2 c) {
    return __builtin_elementwise_fma(a, b, c);   // -> v_pk_fma_f32
}
static __device__ __forceinline__ f2 bc(float s) { f2 r; r.x = s; r.y = s; return r; }

// ---- kernel A: one-time weight transpose into workspace -------------------------
// wt[((ic*3+kd)*9 + kh*3+kw)*16 + oc] = w[(ic*16+oc)*27 + kd*9+kh*3+kw] * log2(e)
__global__ void wprep_kernel(const float* __restrict__ w, float* __restrict__ wt) {
    int idx = threadIdx.x + blockIdx.x * 256;
    if (idx < IC * 27 * OCH) {
        int ic   = idx / (27 * OCH);
        int rem  = idx - ic * (27 * OCH);
        int kpos = rem >> 4;
        int oc   = rem & 15;
        wt[idx] = w[(ic * OCH + oc) * 27 + kpos] * LOG2E;
    }
}

// ---- main kernel ----------------------------------------------------------------
// Fused ConvTranspose3d(3->16,k3,s2,p1) + channel-LSE + x*sigmoid(x+3)/6 - bias, clip [-1,1].
// Round-8 base (no LDS, no barrier, wave-uniform global weight f4s, packed-f2 FMAs, one
// straight-line phase). NEW: explicit 1-deep SOFTWARE PIPELINE on the weight stream --
// named double-buffer WA/WB of 9 f4; load(batch k+1) issued BEFORE consume(batch k) so each
// batch's vmcnt wait sits behind 36 pk-FMAs of independent work (R12 showed the compiler
// does not do this on its own; batch latency ~150cyc vs ~144cyc compute = the 50% duty gap).
// Epilogue trim: sigma(v+3) = S/(S+e^-3) since e^-v = 1/S -> no exp2 in epilogue.
__global__ __launch_bounds__(256, 3) void convt_lse_kernel(
    const float* __restrict__ x, const float* __restrict__ wt,
    const float* __restrict__ bias, float* __restrict__ out)
{
    const int j  = threadIdx.x & 31;                       // ow pair: ow = 2j, 2j+1
    const int i  = (threadIdx.x >> 5) + (blockIdx.x << 3); // oh pair: oh = 2i, 2i+1
    const int od = blockIdx.y;
    const int b  = blockIdx.z;

    const int ih0 = i;
    const int ih1 = min(i + 1, IHH - 1);   // clamp: feeds only non-stored oh=63
    const int iw0 = j;
    const int iw1 = min(j + 1, IWW - 1);   // clamp: feeds only non-stored ow=63

    const bool odd = (od & 1) != 0;
    const int id0 = odd ? ((od + 1) >> 1) : (od >> 1);
    const int id1 = (od - 1) >> 1;         // used only when odd

    // x loads issued first; vmcnt waits land inside the FMA stream
    float xr[2][IC][4];    // [tap][ic][{00,01,10,11}] - compile-time indexed only
    #pragma unroll
    for (int ic = 0; ic < IC; ++ic) {
        const float* __restrict__ xp = x + (((b * IC + ic) * IDD + id0) << 10);
        xr[0][ic][0] = xp[ih0 * IWW + iw0];
        xr[0][ic][1] = xp[ih0 * IWW + iw1];
        xr[0][ic][2] = xp[ih1 * IWW + iw0];
        xr[0][ic][3] = xp[ih1 * IWW + iw1];
    }
    if (odd) {
        #pragma unroll
        for (int ic = 0; ic < IC; ++ic) {
            const float* __restrict__ xp = x + (((b * IC + ic) * IDD + id1) << 10);
            xr[1][ic][0] = xp[ih0 * IWW + iw0];
            xr[1][ic][1] = xp[ih0 * IWW + iw1];
            xr[1][ic][2] = xp[ih1 * IWW + iw0];
            xr[1][ic][3] = xp[ih1 * IWW + iw1];
        }
    }
    const float bv = bias[0];

    // acc[p][cp]: p 0=(ee) 1=(eo) 2=(oe) 3=(oo); cp = oc pair (2 channels)
    f2 acc[4][8];

// Load one q-batch (9 f4, taps 0..8 of quad q) into named buffer W*0..W*8
#define LOADB(W, wp, q)                                                               \
    W##0 = (wp)[0 * 4 + (q)]; W##1 = (wp)[1 * 4 + (q)]; W##2 = (wp)[2 * 4 + (q)];     \
    W##3 = (wp)[3 * 4 + (q)]; W##4 = (wp)[4 * 4 + (q)]; W##5 = (wp)[5 * 4 + (q)];     \
    W##6 = (wp)[6 * 4 + (q)]; W##7 = (wp)[7 * 4 + (q)]; W##8 = (wp)[8 * 4 + (q)];

// Consume one q-batch: 36 pk-fma (R8's proven tap->parity mapping), q/first literal
#define CONS(W, tpi, ic, q, first) {                                                  \
    const f2 x00 = bc(xr[tpi][ic][0]); const f2 x01 = bc(xr[tpi][ic][1]);             \
    const f2 x10 = bc(xr[tpi][ic][2]); const f2 x11 = bc(xr[tpi][ic][3]);             \
    _Pragma("unroll")                                                                 \
    for (int h = 0; h < 2; ++h) {                                                     \
        const int cp = 2 * (q) + h;                                                   \
        const f2 w0 = {W##0[2*h], W##0[2*h+1]}, w1 = {W##1[2*h], W##1[2*h+1]},        \
                 w2 = {W##2[2*h], W##2[2*h+1]}, w3 = {W##3[2*h], W##3[2*h+1]},        \
                 w4 = {W##4[2*h], W##4[2*h+1]}, w5 = {W##5[2*h], W##5[2*h+1]},        \
                 w6 = {W##6[2*h], W##6[2*h+1]}, w7 = {W##7[2*h], W##7[2*h+1]},        \
                 w8 = {W##8[2*h], W##8[2*h+1]};                                       \
        if (first) {                                                                  \
            acc[3][cp] = x11 * w0;                                                    \
            acc[2][cp] = x10 * w1;                                                    \
            acc[1][cp] = x01 * w3;                                                    \
            acc[0][cp] = x00 * w4;                                                    \
        } else {                                                                      \
            acc[3][cp] = fma2(x11, w0, acc[3][cp]);                                   \
            acc[2][cp] = fma2(x10, w1, acc[2][cp]);                                   \
            acc[1][cp] = fma2(x01, w3, acc[1][cp]);                                   \
            acc[0][cp] = fma2(x00, w4, acc[0][cp]);                                   \
        }                                                                             \
        acc[3][cp] = fma2(x10, w2, acc[3][cp]);                                       \
        acc[1][cp] = fma2(x00, w5, acc[1][cp]);                                       \
        acc[3][cp] = fma2(x01, w6, acc[3][cp]);                                       \
        acc[2][cp] = fma2(x00, w7, acc[2][cp]);                                       \
        acc[3][cp] = fma2(x00, w8, acc[3][cp]);                                       \
    } }

    if (odd) {  // 24 batches over 6 planes: kd=0 @ id0 (tpi 0), kd=2 @ id1 (tpi 1)
        const f4* __restrict__ p00 = (const f4*)(wt + (0 * 3 + 0) * 9 * OCH);
        const f4* __restrict__ p01 = (const f4*)(wt + (1 * 3 + 0) * 9 * OCH);
        const f4* __restrict__ p02 = (const f4*)(wt + (2 * 3 + 0) * 9 * OCH);
        const f4* __restrict__ p20 = (const f4*)(wt + (0 * 3 + 2) * 9 * OCH);
        const f4* __restrict__ p21 = (const f4*)(wt + (1 * 3 + 2) * 9 * OCH);
        const f4* __restrict__ p22 = (const f4*)(wt + (2 * 3 + 2) * 9 * OCH);
        f4 WA0, WA1, WA2, WA3, WA4, WA5, WA6, WA7, WA8;
        f4 WB0, WB1, WB2, WB3, WB4, WB5, WB6, WB7, WB8;
        LOADB(WA, p00, 0)
        LOADB(WB, p00, 1) CONS(WA, 0, 0, 0, true)
        LOADB(WA, p00, 2) CONS(WB, 0, 0, 1, true)
        LOADB(WB, p00, 3) CONS(WA, 0, 0, 2, true)
        LOADB(WA, p01, 0) CONS(WB, 0, 0, 3, true)
        LOADB(WB, p01, 1) CONS(WA, 0, 1, 0, false)
        LOADB(WA, p01, 2) CONS(WB, 0, 1, 1, false)
        LOADB(WB, p01, 3) CONS(WA, 0, 1, 2, false)
        LOADB(WA, p02, 0) CONS(WB, 0, 1, 3, false)
        LOADB(WB, p02, 1) CONS(WA, 0, 2, 0, false)
        LOADB(WA, p02, 2) CONS(WB, 0, 2, 1, false)
        LOADB(WB, p02, 3) CONS(WA, 0, 2, 2, false)
        LOADB(WA, p20, 0) CONS(WB, 0, 2, 3, false)
        LOADB(WB, p20, 1) CONS(WA, 1, 0, 0, false)
        LOADB(WA, p20, 2) CONS(WB, 1, 0, 1, false)
        LOADB(WB, p20, 3) CONS(WA, 1, 0, 2, false)
        LOADB(WA, p21, 0) CONS(WB, 1, 0, 3, false)
        LOADB(WB, p21, 1) CONS(WA, 1, 1, 0, false)
        LOADB(WA, p21, 2) CONS(WB, 1, 1, 1, false)
        LOADB(WB, p21, 3) CONS(WA, 1, 1, 2, false)
        LOADB(WA, p22, 0) CONS(WB, 1, 1, 3, false)
        LOADB(WB, p22, 1) CONS(WA, 1, 2, 0, false)
        LOADB(WA, p22, 2) CONS(WB, 1, 2, 1, false)
        LOADB(WB, p22, 3) CONS(WA, 1, 2, 2, false)
                          CONS(WB, 1, 2, 3, false)
    } else {    // 12 batches over 3 planes: kd=1 @ id0 (tpi 0)
        const f4* __restrict__ pA = (const f4*)(wt + (0 * 3 + 1) * 9 * OCH);
        const f4* __restrict__ pB = (const f4*)(wt + (1 * 3 + 1) * 9 * OCH);
        const f4* __restrict__ pC = (const f4*)(wt + (2 * 3 + 1) * 9 * OCH);
        f4 WA0, WA1, WA2, WA3, WA4, WA5, WA6, WA7, WA8;
        f4 WB0, WB1, WB2, WB3, WB4, WB5, WB6, WB7, WB8;
        LOADB(WA, pA, 0)
        LOADB(WB, pA, 1) CONS(WA, 0, 0, 0, true)
        LOADB(WA, pA, 2) CONS(WB, 0, 0, 1, true)
        LOADB(WB, pA, 3) CONS(WA, 0, 0, 2, true)
        LOADB(WA, pB, 0) CONS(WB, 0, 0, 3, true)
        LOADB(WB, pB, 1) CONS(WA, 0, 1, 0, false)
        LOADB(WA, pB, 2) CONS(WB, 0, 1, 1, false)
        LOADB(WB, pB, 3) CONS(WA, 0, 1, 2, false)
        LOADB(WA, pC, 0) CONS(WB, 0, 1, 3, false)
        LOADB(WB, pC, 1) CONS(WA, 0, 2, 0, false)
        LOADB(WA, pC, 2) CONS(WB, 0, 2, 1, false)
        LOADB(WB, pC, 3) CONS(WA, 0, 2, 2, false)
                         CONS(WB, 0, 2, 3, false)
    }

    const int oh0   = 2 * i;
    const int ow0   = 2 * j;
    const int obase = (b * ODD + od) * OHH;

    #pragma unroll
    for (int p = 0; p < 4; ++p) {
        const int oh = oh0 + (p >> 1);
        const int ow = ow0 + (p & 1);
        if (oh < OHH && ow < OWW) {
            // acc is log2-domain: S = sum exp2(acc); no max-sub (|acc| bounded << 126)
            f2 sa = {0.0f, 0.0f}, sb = {0.0f, 0.0f};
            #pragma unroll
            for (int cp = 0; cp < 8; cp += 2) {
                f2 ea, eb;
                ea.x = __builtin_amdgcn_exp2f(acc[p][cp].x);
                ea.y = __builtin_amdgcn_exp2f(acc[p][cp].y);
                eb.x = __builtin_amdgcn_exp2f(acc[p][cp + 1].x);
                eb.y = __builtin_amdgcn_exp2f(acc[p][cp + 1].y);
                sa += ea;                       // v_pk_add_f32
                sb += eb;
            }
            const f2 st   = sa + sb;
            const float S = st.x + st.y;
            const float v = LN2 * __builtin_amdgcn_logf(S);          // ln(S)
            // sigma(v+3) = S/(S+e^-3)  (e^-v = 1/S)  ->  hs = v*S/(6S + 6e^-3)
            const float hs = v * S * __builtin_amdgcn_rcpf(fmaf(6.0f, S, SIX_EXP_M3));
            const float r  = fminf(1.0f, fmaxf(-1.0f, hs - bv));
            out[(obase + oh) * OWW + ow] = r;
        }
    }
}

extern "C" void kernel_launch(void* const* d_in, const int* in_sizes, int n_in,
                              void* d_out, int out_size, void* d_ws, size_t ws_size,
                              hipStream_t stream) {
    const float* x    = (const float*)d_in[0];
    const float* w    = (const float*)d_in[1];
    const float* bias = (const float*)d_in[2];
    float* out        = (float*)d_out;
    float* wt         = (float*)d_ws;     // 1296 floats = 5.2 KB scratch

    wprep_kernel<<<dim3(6), dim3(256), 0, stream>>>(w, wt);

    dim3 grid(4, ODD, NB);   // 4 i-chunks (8 i-values each) x od x batch
    dim3 block(256);
    convt_lse_kernel<<<grid, block, 0, stream>>>(x, wt, bias, out);
}

// Round 14
// 87.511 us; speedup vs baseline: 1.1090x; 1.1090x over previous
//
#include <hip/hip_runtime.h>

#define IC 3
#define OCH 16
#define IDD 16
#define IHH 32
#define IWW 32
#define ODD 31
#define OHH 63
#define OWW 63
#define NB 32

typedef float f2 __attribute__((ext_vector_type(2)));
typedef float f4 __attribute__((ext_vector_type(4)));

#define LOG2E 1.44269504088896340736f
#define LN2   0.69314718055994530942f
#define SIX_EXP_M3 0.2987224102071593f   // 6*e^-3

static __device__ __forceinline__ f2 fma2(f2 a, f2 b, f2 c) {
    return __builtin_elementwise_fma(a, b, c);   // -> v_pk_fma_f32
}

// ---- kernel A: one-time weight transpose into workspace -------------------------
// wt[((ic*3+kd)*9 + kh*3+kw)*16 + oc] = w[(ic*16+oc)*27 + kd*9+kh*3+kw] * log2(e)
__global__ void wprep_kernel(const float* __restrict__ w, float* __restrict__ wt) {
    int idx = threadIdx.x + blockIdx.x * 256;
    if (idx < IC * 27 * OCH) {
        int ic   = idx / (27 * OCH);
        int rem  = idx - ic * (27 * OCH);
        int kpos = rem >> 4;
        int oc   = rem & 15;
        wt[idx] = w[(ic * OCH + oc) * 27 + kpos] * LOG2E;
    }
}

// ---- main kernel ----------------------------------------------------------------
// Fused ConvTranspose3d(3->16,k3,s2,p1) + channel-LSE + x*sigmoid(x+3)/6 - bias, clip [-1,1].
// FINAL: round-8's proven shape verbatim -- the best harness-verified variant (86.7 us).
//  * parity decomposition, 2x2 patch/thread, one od per thread, straight-line single phase
//  * no LDS, no __syncthreads: weights via wave-uniform global f4 loads from the
//    pre-transposed 5 KB table (L1-resident broadcast); compiler schedules load batches
//  * packed-f2 (v_pk_fma_f32) accumulators in exp2 domain (weights pre-scaled by log2 e)
//  * epilogue identity (validated R12/R13): e^-v = 1/S  =>  sigma(v+3) = S/(S+e^-3),
//    so hs = v*S/(6S + 6e^-3) -- no exp2 in the epilogue.
// 13 rounds of counter-driven A/B established: LDS staging variants, od-pairing, oc-split,
// wave/block-count changes, and explicit software pipelining are all flat-to-regressive;
// only instruction-count cuts and barrier removal moved the wall.
__global__ __launch_bounds__(256, 4) void convt_lse_kernel(
    const float* __restrict__ x, const float* __restrict__ wt,
    const float* __restrict__ bias, float* __restrict__ out)
{
    const int j  = threadIdx.x & 31;                       // ow pair: ow = 2j, 2j+1
    const int i  = (threadIdx.x >> 5) + (blockIdx.x << 3); // oh pair: oh = 2i, 2i+1
    const int od = blockIdx.y;
    const int b  = blockIdx.z;

    const int ih0 = i;
    const int ih1 = min(i + 1, IHH - 1);   // clamp: feeds only non-stored oh=63
    const int iw0 = j;
    const int iw1 = min(j + 1, IWW - 1);   // clamp: feeds only non-stored ow=63

    const bool odd = (od & 1) != 0;
    const int id0 = odd ? ((od + 1) >> 1) : (od >> 1);
    const int id1 = (od - 1) >> 1;         // used only when odd

    // x loads issued first; vmcnt waits land inside the FMA stream
    float xr[2][IC][4];    // [tap][ic][{00,01,10,11}] - compile-time indexed only
    #pragma unroll
    for (int ic = 0; ic < IC; ++ic) {
        const float* __restrict__ xp = x + (((b * IC + ic) * IDD + id0) << 10);
        xr[0][ic][0] = xp[ih0 * IWW + iw0];
        xr[0][ic][1] = xp[ih0 * IWW + iw1];
        xr[0][ic][2] = xp[ih1 * IWW + iw0];
        xr[0][ic][3] = xp[ih1 * IWW + iw1];
    }
    if (odd) {
        #pragma unroll
        for (int ic = 0; ic < IC; ++ic) {
            const float* __restrict__ xp = x + (((b * IC + ic) * IDD + id1) << 10);
            xr[1][ic][0] = xp[ih0 * IWW + iw0];
            xr[1][ic][1] = xp[ih0 * IWW + iw1];
            xr[1][ic][2] = xp[ih1 * IWW + iw0];
            xr[1][ic][3] = xp[ih1 * IWW + iw1];
        }
    }
    const float bv = bias[0];

    // acc[p][cp]: p 0=(ee) 1=(eo) 2=(oe) 3=(oo); cp = oc pair (2 channels)
    f2 acc[4][8];

// 9 f4 weight loads (wave-uniform addr -> L1 broadcast) feeding 18 pk-fma per (ic,q)
#define TAPQ(first, x00, x01, x10, x11, wq)                                           \
    {                                                                                 \
        _Pragma("unroll")                                                             \
        for (int q = 0; q < 4; ++q) {                                                 \
            const f4 W0 = wq[0 * 4 + q], W1 = wq[1 * 4 + q], W2 = wq[2 * 4 + q],      \
                     W3 = wq[3 * 4 + q], W4 = wq[4 * 4 + q], W5 = wq[5 * 4 + q],      \
                     W6 = wq[6 * 4 + q], W7 = wq[7 * 4 + q], W8 = wq[8 * 4 + q];      \
            _Pragma("unroll")                                                         \
            for (int h = 0; h < 2; ++h) {                                             \
                const int cp = 2 * q + h;                                             \
                const f2 w0 = {W0[2*h], W0[2*h+1]}, w1 = {W1[2*h], W1[2*h+1]},        \
                         w2 = {W2[2*h], W2[2*h+1]}, w3 = {W3[2*h], W3[2*h+1]},        \
                         w4 = {W4[2*h], W4[2*h+1]}, w5 = {W5[2*h], W5[2*h+1]},        \
                         w6 = {W6[2*h], W6[2*h+1]}, w7 = {W7[2*h], W7[2*h+1]},        \
                         w8 = {W8[2*h], W8[2*h+1]};                                   \
                if (first) {                                                          \
                    acc[3][cp] = x11 * w0;                                            \
                    acc[2][cp] = x10 * w1;                                            \
                    acc[1][cp] = x01 * w3;                                            \
                    acc[0][cp] = x00 * w4;                                            \
                } else {                                                              \
                    acc[3][cp] = fma2(x11, w0, acc[3][cp]);                           \
                    acc[2][cp] = fma2(x10, w1, acc[2][cp]);                           \
                    acc[1][cp] = fma2(x01, w3, acc[1][cp]);                           \
                    acc[0][cp] = fma2(x00, w4, acc[0][cp]);                           \
                }                                                                     \
                acc[3][cp] = fma2(x10, w2, acc[3][cp]);                               \
                acc[1][cp] = fma2(x00, w5, acc[1][cp]);                               \
                acc[3][cp] = fma2(x01, w6, acc[3][cp]);                               \
                acc[2][cp] = fma2(x00, w7, acc[2][cp]);                               \
                acc[3][cp] = fma2(x00, w8, acc[3][cp]);                               \
            }                                                                         \
        }                                                                             \
    }

#define DO_TAP(kd, tpi, first)                                                        \
    {                                                                                 \
        _Pragma("unroll")                                                             \
        for (int ic = 0; ic < IC; ++ic) {                                             \
            const f2 x00 = {xr[tpi][ic][0], xr[tpi][ic][0]};                          \
            const f2 x01 = {xr[tpi][ic][1], xr[tpi][ic][1]};                          \
            const f2 x10 = {xr[tpi][ic][2], xr[tpi][ic][2]};                          \
            const f2 x11 = {xr[tpi][ic][3], xr[tpi][ic][3]};                          \
            const f4* __restrict__ wq = (const f4*)(wt + (ic * 3 + (kd)) * 9 * OCH);  \
            TAPQ((first) && ic == 0, x00, x01, x10, x11, wq)                          \
        }                                                                             \
    }

    if (odd) {          // odd od: kd=0 @ id0=(od+1)/2, kd=2 @ id1=(od-1)/2
        DO_TAP(0, 0, true)
        DO_TAP(2, 1, false)
    } else {            // even od: kd=1 @ id0=od/2
        DO_TAP(1, 0, true)
    }

    const int oh0   = 2 * i;
    const int ow0   = 2 * j;
    const int obase = (b * ODD + od) * OHH;

    #pragma unroll
    for (int p = 0; p < 4; ++p) {
        const int oh = oh0 + (p >> 1);
        const int ow = ow0 + (p & 1);
        if (oh < OHH && ow < OWW) {
            // acc is log2-domain: S = sum exp2(acc); no max-sub (|acc| bounded << 126)
            f2 sa = {0.0f, 0.0f}, sb = {0.0f, 0.0f};
            #pragma unroll
            for (int cp = 0; cp < 8; cp += 2) {
                f2 ea, eb;
                ea.x = __builtin_amdgcn_exp2f(acc[p][cp].x);
                ea.y = __builtin_amdgcn_exp2f(acc[p][cp].y);
                eb.x = __builtin_amdgcn_exp2f(acc[p][cp + 1].x);
                eb.y = __builtin_amdgcn_exp2f(acc[p][cp + 1].y);
                sa += ea;                       // v_pk_add_f32
                sb += eb;
            }
            const f2 st   = sa + sb;
            const float S = st.x + st.y;
            const float v = LN2 * __builtin_amdgcn_logf(S);          // ln(S)
            // sigma(v+3) = S/(S+e^-3)  (since e^-v = 1/S)  ->  hs = v*S/(6S + 6e^-3)
            const float hs = v * S * __builtin_amdgcn_rcpf(fmaf(6.0f, S, SIX_EXP_M3));
            const float r  = fminf(1.0f, fmaxf(-1.0f, hs - bv));
            out[(obase + oh) * OWW + ow] = r;
        }
    }
}

extern "C" void kernel_launch(void* const* d_in, const int* in_sizes, int n_in,
                              void* d_out, int out_size, void* d_ws, size_t ws_size,
                              hipStream_t stream) {
    const float* x    = (const float*)d_in[0];
    const float* w    = (const float*)d_in[1];
    const float* bias = (const float*)d_in[2];
    float* out        = (float*)d_out;
    float* wt         = (float*)d_ws;     // 1296 floats = 5.2 KB scratch

    wprep_kernel<<<dim3(6), dim3(256), 0, stream>>>(w, wt);

    dim3 grid(4, ODD, NB);   // 4 i-chunks (8 i-values each) x od x batch
    dim3 block(256);
    convt_lse_kernel<<<grid, block, 0, stream>>>(x, wt, bias, out);
}